// Round 14
// baseline (339.715 us; speedup 1.0000x reference)
//
#include <hip/hip_runtime.h>
#include <cstdint>
#include <cstddef>

#define DMODEL 1024
#define DH 2048
#define BATCH 2
#define SEQ 4096
#define MROWS (BATCH*SEQ)    // 8192
#define CHUNK 64
#define NCHUNK (SEQ/CHUNK)   // 64

typedef unsigned short u16;
typedef __attribute__((ext_vector_type(8))) short bf16x8;
typedef __attribute__((ext_vector_type(4))) float f32x4;

__device__ __forceinline__ u16 f2bf(float f) {
    union { float f; unsigned u; } v; v.f = f;
    unsigned r = v.u + 0x7FFFu + ((v.u >> 16) & 1u);
    return (u16)(r >> 16);
}
__device__ __forceinline__ float bf2f(u16 h) {
    union { unsigned u; float f; } v; v.u = ((unsigned)h) << 16; return v.f;
}

__device__ __forceinline__ float softplus_fast(float x) {
    if (x < -4.f) return __expf(x);
    return (x > 0.f) ? (x + log1pf(__expf(-x))) : log1pf(__expf(x));
}
__device__ __forceinline__ float silu_fast(float v) {
    return v * __fdividef(1.f, 1.f + __expf(-v));
}

// ---------------- f32 -> bf16, 4 elems/thread ----------------
__global__ void cvt_bf16(const float* __restrict__ src, u16* __restrict__ dst, int n4) {
    int i = blockIdx.x * blockDim.x + threadIdx.x;
    if (i >= n4) return;
    const float4 v = reinterpret_cast<const float4*>(src)[i];
    ushort4 o;
    o.x = f2bf(v.x); o.y = f2bf(v.y); o.z = f2bf(v.z); o.w = f2bf(v.w);
    reinterpret_cast<ushort4*>(dst)[i] = o;
}

__device__ __forceinline__ void gload_lds16(const void* g, void* l) {
    __builtin_amdgcn_global_load_lds(
        (const __attribute__((address_space(1))) void*)g,
        (__attribute__((address_space(3))) void*)l,
        16, 0, 0);
}

// ================= 8-phase 256x256 pipeline GEMM (m201 template port) =================
// Merged delta|pBv GEMM only (EP4). BM=BN=256, BK=64, 512 thr / 8 waves (2M x 4N),
// per-wave 128x64 out with INTERLEAVED rows (frag m -> row m*32 + gm*16): A-halves are
// consumed 2 phases each; B goes to registers at phase 0 (frees B LDS immediately).
// 2 buffers (tile t -> buf t%2), 4 phases/tile; stage slots: q0: A-h1(t+1);
// q1/q2/q3: B-h0/B-h1/A-h0 of (t+2) -- each into a region freed exactly one phase ago.
// vmcnt(6) once per tile (q3): guarantees tile t+1 fully landed with t+2's 6 loads
// still in flight (counted-vmcnt, never drains mid-loop). Per phase:
// {ds_read 12|4 x b128; stage 2 gload_lds; barrier; lgkmcnt(0); setprio(1);
//  16 MFMA; setprio(0); [vmcnt]; barrier}. LDS 128 KB, 1 block/CU, 2 waves/SIMD.
template<int EP>
__global__ __launch_bounds__(512, 2) void gemm8p(
    const u16* __restrict__ A, const u16* __restrict__ Bm, int K,
    u16* __restrict__ Cb, u16* __restrict__ Cb2,
    const float* __restrict__ bias, const float* __restrict__ bias2,
    int M, int N)
{
    __shared__ __align__(16) char smem[131072];
    const int tid = threadIdx.x;

    // XCD chunk swizzle + 8x8 supertile (grids: 16x32 / 16x16; nwg%8==0)
    const int nwg = gridDim.x * gridDim.y;
    int wg = blockIdx.y * gridDim.x + blockIdx.x;
    wg = (wg & 7) * (nwg >> 3) + (wg >> 3);
    const int stile = wg >> 6;
    const int t64   = wg & 63;
    const int nSn   = gridDim.x >> 3;
    const int sm = (nSn > 0) ? stile / nSn : stile;
    const int sn = (nSn > 0) ? stile - sm * nSn : 0;
    const int m0 = (sm * 8 + (t64 >> 3)) * 256;
    const int n0 = (sn * 8 + (t64 & 7)) * 256;

    const int wave = tid >> 6, lane = tid & 63;
    const int gm16 = (wave >> 2) * 16;       // wave M-group offset (rows interleaved)
    const int gn   = wave & 3;               // wave N-group (64 cols each)
    const int fr = lane & 15, fq = lane >> 4;
    const int fx = fr & 7;

    f32x4 acc[8][4];
    #pragma unroll
    for (int m = 0; m < 8; m++)
        #pragma unroll
        for (int n = 0; n < 4; n++) acc[m][n] = f32x4{0.f, 0.f, 0.f, 0.f};

    const int nt = K >> 6;   // 16 for K=1024 (even)

    // stage one half-tile (128 rows x 64 cols bf16 = 16 KB = 2 gload_lds/thread)
    auto stage_half = [&](int t, int isB, int h) {
        const u16* src = isB ? Bm : A;
        const int base0 = (isB ? n0 : m0) + h * 128;
        char* dst = smem + (size_t)(((t & 1) * 65536) + isB * 32768 + h * 16384);
        #pragma unroll
        for (int j = 0; j < 2; ++j) {
            const int g = j*512 + tid;           // 0..1023 granules of 16B
            const int r = g >> 3;                // row in half (0..127)
            const int ch = (g & 7) ^ (r & 7);    // pre-swizzled source chunk (rule 21)
            gload_lds16(src + (size_t)(base0 + r)*K + (t*64 + ch*8), dst + (size_t)g*16);
        }
    };

    // prologue: tile0 fully (B0,B1,A0,A1) + tile1 (B0,B1,A0); A1(1) comes at t0q0
    stage_half(0,1,0); stage_half(0,1,1); stage_half(0,0,0); stage_half(0,0,1);
    stage_half(1,1,0); stage_half(1,1,1); stage_half(1,0,0);
    asm volatile("s_waitcnt vmcnt(6)" ::: "memory");   // tile0's 8 loads landed
    __builtin_amdgcn_s_barrier();
    __builtin_amdgcn_sched_barrier(0);

    for (int t = 0; t < nt; ++t) {
        const char* Abase = smem + (t & 1) * 65536;
        const char* Bbase = Abase + 32768;
        bf16x8 bfr[4][2];
        #pragma unroll
        for (int q = 0; q < 4; ++q) {
            // ds_read this phase's A-quad (frags 2q, 2q+1)
            bf16x8 af[2][2];
            #pragma unroll
            for (int i = 0; i < 2; ++i) {
                const int m = 2*q + i;
                const int rl = (m & 3)*32 + gm16 + fr;    // row within half
                #pragma unroll
                for (int kk = 0; kk < 2; ++kk)
                    af[i][kk] = *reinterpret_cast<const bf16x8*>(
                        Abase + (m >> 2)*16384 + rl*128 + (((kk*4 + fq) ^ fx) * 16));
            }
            if (q == 0) {   // B-frags -> registers (frees B LDS after this phase)
                #pragma unroll
                for (int n = 0; n < 4; ++n) {
                    const int cl = (gn & 1)*64 + n*16 + fr;
                    #pragma unroll
                    for (int kk = 0; kk < 2; ++kk)
                        bfr[n][kk] = *reinterpret_cast<const bf16x8*>(
                            Bbase + (gn >> 1)*16384 + cl*128 + (((kk*4 + fq) ^ fx) * 16));
                }
            }
            // stage slot (each target region freed exactly one phase earlier)
            if (q == 0) { if (t + 1 < nt) stage_half(t + 1, 0, 1); }
            else if (t + 2 < nt) {
                if (q == 1)      stage_half(t + 2, 1, 0);
                else if (q == 2) stage_half(t + 2, 1, 1);
                else             stage_half(t + 2, 0, 0);
            }
            __builtin_amdgcn_s_barrier();
            asm volatile("s_waitcnt lgkmcnt(0)" ::: "memory");
            __builtin_amdgcn_sched_barrier(0);
            __builtin_amdgcn_s_setprio(1);
            #pragma unroll
            for (int i = 0; i < 2; ++i)
                #pragma unroll
                for (int n = 0; n < 4; ++n)
                    #pragma unroll
                    for (int kk = 0; kk < 2; ++kk)
                        acc[2*q + i][n] = __builtin_amdgcn_mfma_f32_16x16x32_bf16(
                            af[i][kk], bfr[n][kk], acc[2*q + i][n], 0, 0, 0);
            __builtin_amdgcn_s_setprio(0);
            if (q == 3) {   // counted checkpoint: tile t+1 fully landed (t+2's 6 fly)
                if (t + 2 < nt) { asm volatile("s_waitcnt vmcnt(6)" ::: "memory"); }
                else            { asm volatile("s_waitcnt vmcnt(0)" ::: "memory"); }
            }
            __builtin_amdgcn_s_barrier();
            __builtin_amdgcn_sched_barrier(0);
        }
    }

    // ---------- coalesced epilogue: 8 chunks of 32 rows through LDS ----------
    float* ep = (float*)smem;          // [32][260] f32 = 33.3 KB
    const bool isDelta = (EP == 4) ? (n0 < DH) : false;
    #pragma unroll
    for (int c = 0; c < 8; ++c) {
        #pragma unroll
        for (int n = 0; n < 4; ++n) {
            const int col = gn*64 + n*16 + fr;
            #pragma unroll
            for (int j = 0; j < 4; ++j)
                ep[(gm16 + fq*4 + j)*260 + col] = acc[c][n][j];
        }
        __syncthreads();
        #pragma unroll
        for (int p = 0; p < 4; ++p) {
            const int idx = p*512 + tid;        // 2048 float4 per chunk
            const int row = idx >> 6, c4 = idx & 63;
            float4 v = *reinterpret_cast<const float4*>(&ep[row*260 + c4*4]);
            const int rg   = m0 + c*32 + row;   // frag m=c rows interleave to c*32..+31
            const int colg = n0 + c4*4;
            if constexpr (EP == 4) {
                const int cc = isDelta ? colg : (colg - DH);
                const float4 bv = *reinterpret_cast<const float4*>(
                    (isDelta ? bias : bias2) + cc);
                ushort4 o;
                if (isDelta) {
                    o.x = f2bf(softplus_fast(v.x + bv.x));
                    o.y = f2bf(softplus_fast(v.y + bv.y));
                    o.z = f2bf(softplus_fast(v.z + bv.z));
                    o.w = f2bf(softplus_fast(v.w + bv.w));
                } else {
                    o.x = f2bf(v.x + bv.x); o.y = f2bf(v.y + bv.y);
                    o.z = f2bf(v.z + bv.z); o.w = f2bf(v.w + bv.w);
                }
                *reinterpret_cast<ushort4*>((isDelta ? Cb : Cb2) + (size_t)rg*DH + cc) = o;
            } else {
                float4 b1 = {0,0,0,0};
                if (bias) b1 = *reinterpret_cast<const float4*>(bias + colg);
                ushort4 o = { f2bf(v.x + b1.x), f2bf(v.y + b1.y),
                              f2bf(v.z + b1.z), f2bf(v.w + b1.w) };
                *reinterpret_cast<ushort4*>(Cb + (size_t)rg*N + colg) = o;
            }
        }
        __syncthreads();
    }
}

// ================= R13 GEMM (m97 structure + coalesced epilogue), other ops ==========
template<int EP, bool TWOK>
__global__ __launch_bounds__(256, 4) void gemm_bt(
    const u16* __restrict__ A1, const u16* __restrict__ B1, int K1,
    const u16* __restrict__ A2, const u16* __restrict__ B2, int K2,
    float* __restrict__ C, u16* __restrict__ Cb, u16* __restrict__ Cb2,
    const float* __restrict__ bias, const float* __restrict__ bias2,
    const float* __restrict__ aux,
    int M, int N)
{
    __shared__ __align__(16) char smem[32768];
    u16* As = (u16*)smem;              // [128 rows][8 chunks of 16B], swizzled
    u16* Bs = (u16*)(smem + 16384);
    float* ep = (float*)smem;          // epilogue scratch [32][132] f32

    const int tid = threadIdx.x;

    const int nwg = gridDim.x * gridDim.y;
    int wg = blockIdx.y * gridDim.x + blockIdx.x;
    wg = (wg & 7) * (nwg >> 3) + (wg >> 3);
    const int stile = wg >> 6;
    const int t64   = wg & 63;
    const int nSn   = gridDim.x >> 3;
    const int sm = (nSn > 0) ? stile / nSn : stile;
    const int sn = (nSn > 0) ? stile - sm * nSn : 0;
    const int m0 = (sm * 8 + (t64 >> 3)) * 128;
    const int n0 = (sn * 8 + (t64 & 7)) * 128;

    const int wave = tid >> 6, lane = tid & 63;
    const int wr = (wave >> 1) * 64;
    const int wc = (wave & 1) * 64;
    const int fr = lane & 15, fq = lane >> 4;

    f32x4 acc[4][4];
    #pragma unroll
    for (int m = 0; m < 4; m++)
        #pragma unroll
        for (int n = 0; n < 4; n++) acc[m][n] = f32x4{0.f, 0.f, 0.f, 0.f};

    const int nt1 = K1 >> 6;
    const int nt  = TWOK ? nt1 + (K2 >> 6) : nt1;

    for (int t = 0; t < nt; ++t) {
        const u16* A = A1; const u16* B = B1; int K = K1; int k0 = t << 6;
        if (TWOK && t >= nt1) { A = A2; B = B2; K = K2; k0 = (t - nt1) << 6; }
        #pragma unroll
        for (int i = 0; i < 4; ++i) {
            const int g = i*256 + tid;
            const int r = g >> 3;
            const int ch = (g & 7) ^ (r & 7);
            gload_lds16(A + (size_t)(m0 + r)*K + (k0 + ch*8), (char*)As + (size_t)g*16);
            gload_lds16(B + (size_t)(n0 + r)*K + (k0 + ch*8), (char*)Bs + (size_t)g*16);
        }
        __syncthreads();

        #pragma unroll
        for (int kk = 0; kk < 2; ++kk) {
            bf16x8 af[4], bfr[4];
            #pragma unroll
            for (int m = 0; m < 4; m++) {
                const int r = wr + m*16 + fr;
                af[m] = *reinterpret_cast<const bf16x8*>(
                    (const char*)As + r*128 + (((kk*4 + fq) ^ (r & 7)) * 16));
            }
            #pragma unroll
            for (int n = 0; n < 4; n++) {
                const int r = wc + n*16 + fr;
                bfr[n] = *reinterpret_cast<const bf16x8*>(
                    (const char*)Bs + r*128 + (((kk*4 + fq) ^ (r & 7)) * 16));
            }
            #pragma unroll
            for (int m = 0; m < 4; m++)
                #pragma unroll
                for (int n = 0; n < 4; n++)
                    acc[m][n] = __builtin_amdgcn_mfma_f32_16x16x32_bf16(af[m], bfr[n], acc[m][n], 0, 0, 0);
        }
        __syncthreads();
    }

    const bool isDelta = (EP == 4) ? (n0 < DH) : false;
    #pragma unroll
    for (int c = 0; c < 4; ++c) {
        if ((wave >> 1) == (c >> 1)) {
            const int mb = (c & 1) * 2;
            #pragma unroll
            for (int mi = 0; mi < 2; mi++) {
                #pragma unroll
                for (int n = 0; n < 4; n++) {
                    const int col = wc + n*16 + fr;
                    #pragma unroll
                    for (int j = 0; j < 4; j++)
                        ep[(mi*16 + fq*4 + j)*132 + col] = acc[mb + mi][n][j];
                }
            }
        }
        __syncthreads();
        #pragma unroll
        for (int p = 0; p < 4; ++p) {
            const int idx = p*256 + tid;
            const int row = idx >> 5, c4 = idx & 31;
            float4 v = *reinterpret_cast<const float4*>(&ep[row*132 + c4*4]);
            const int rg   = m0 + c*32 + row;
            const int colg = n0 + c4*4;
            if constexpr (EP == 4) {
                const int cc = isDelta ? colg : (colg - DH);
                const float4 bv = *reinterpret_cast<const float4*>(
                    (isDelta ? bias : bias2) + cc);
                ushort4 o;
                if (isDelta) {
                    o.x = f2bf(softplus_fast(v.x + bv.x));
                    o.y = f2bf(softplus_fast(v.y + bv.y));
                    o.z = f2bf(softplus_fast(v.z + bv.z));
                    o.w = f2bf(softplus_fast(v.w + bv.w));
                } else {
                    o.x = f2bf(v.x + bv.x); o.y = f2bf(v.y + bv.y);
                    o.z = f2bf(v.z + bv.z); o.w = f2bf(v.w + bv.w);
                }
                *reinterpret_cast<ushort4*>((isDelta ? Cb : Cb2) + (size_t)rg*DH + cc) = o;
            } else {
                if (bias) {
                    const float4 b1 = *reinterpret_cast<const float4*>(bias + colg);
                    v.x += b1.x; v.y += b1.y; v.z += b1.z; v.w += b1.w;
                }
                if (bias2) {
                    const float4 b2 = *reinterpret_cast<const float4*>(bias2 + colg);
                    v.x += b2.x; v.y += b2.y; v.z += b2.z; v.w += b2.w;
                }
                const size_t gidx = (size_t)rg * N + colg;
                if constexpr (EP == 0) {
                    ushort4 o = { f2bf(v.x), f2bf(v.y), f2bf(v.z), f2bf(v.w) };
                    *reinterpret_cast<ushort4*>(Cb + gidx) = o;
                } else if constexpr (EP == 1) {
                    *reinterpret_cast<float4*>(C + gidx) = v;
                    ushort4 o = { f2bf(v.x), f2bf(v.y), f2bf(v.z), f2bf(v.w) };
                    *reinterpret_cast<ushort4*>(Cb + gidx) = o;
                } else if constexpr (EP == 2) {
                    const float4 a = *reinterpret_cast<const float4*>(aux + gidx);
                    ushort4 o = { f2bf(a.x * silu_fast(v.x)), f2bf(a.y * silu_fast(v.y)),
                                  f2bf(a.z * silu_fast(v.z)), f2bf(a.w * silu_fast(v.w)) };
                    *reinterpret_cast<ushort4*>(Cb + gidx) = o;
                } else {   // EP 3
                    const float4 a = *reinterpret_cast<const float4*>(aux + gidx);
                    float4 o = { a.x + v.x, a.y + v.y, a.z + v.z, a.w + v.w };
                    *reinterpret_cast<float4*>(C + gidx) = o;
                }
            }
        }
        __syncthreads();
    }
}

// ---------------- depthwise conv3 (pad 1, per seq of 4096) + silu, bf16x8 ----------------
__global__ void conv_silu8(const u16* __restrict__ x1, const float* __restrict__ cw,
                           const float* __restrict__ cb, u16* __restrict__ xab) {
    int t = blockIdx.x * blockDim.x + threadIdx.x;
    int c8  = t & (DMODEL/8 - 1);
    int row = t >> 7;
    int l = row & (SEQ - 1);
    const int c0 = c8 * 8;
    const size_t i0 = (size_t)row * DMODEL + c0;
    bf16x8 v0 = *reinterpret_cast<const bf16x8*>(x1 + i0);
    bf16x8 vm = {}; if (l > 0)       vm = *reinterpret_cast<const bf16x8*>(x1 + i0 - DMODEL);
    bf16x8 vp = {}; if (l < SEQ - 1) vp = *reinterpret_cast<const bf16x8*>(x1 + i0 + DMODEL);
    if (l == 0)       vm = bf16x8{};
    if (l == SEQ - 1) vp = bf16x8{};
    bf16x8 o;
    #pragma unroll
    for (int j = 0; j < 8; ++j) {
        const int c = c0 + j;
        float v = cw[c*3+0]*bf2f((u16)vm[j]) + cw[c*3+1]*bf2f((u16)v0[j])
                + cw[c*3+2]*bf2f((u16)vp[j]) + cb[c];
        o[j] = (short)f2bf(silu_fast(v));
    }
    *reinterpret_cast<bf16x8*>(xab + i0) = o;
}

// ---------------- SSM chunked scan (batch in grid.z) ----------------
__global__ void scan_chunks(const u16* __restrict__ delta, const u16* __restrict__ pBv,
                            const float* __restrict__ Avec,
                            float* __restrict__ cA, float* __restrict__ cB) {
    const int c = blockIdx.x * blockDim.x + threadIdx.x;
    const int q = blockIdx.y;
    const int b = blockIdx.z;
    const float Ac = Avec[c];
    float hA = 1.f, hB = 0.f;
    size_t base = ((size_t)b*SEQ + q*CHUNK)*DH + c;
    for (int j = 0; j < CHUNK; ++j) {
        float d = bf2f(delta[base]);
        float Abar = __expf(d * Ac);
        hA *= Abar;
        hB = Abar*hB + d * bf2f(pBv[base]);
        base += DH;
    }
    size_t o = ((size_t)b*NCHUNK + q)*DH + c;
    cA[o] = hA; cB[o] = hB;
}

__global__ void scan_prefix(const float* __restrict__ cA, const float* __restrict__ cB,
                            float* __restrict__ cH) {
    const int t = blockIdx.x * blockDim.x + threadIdx.x;
    const int b = t >> 11;
    const int c = t & (DH - 1);
    float h = 0.f;
    size_t o = ((size_t)b*NCHUNK)*DH + c;
    float a = cA[o], bb = cB[o];
    for (int q = 0; q < NCHUNK; ++q) {
        const size_t on = o + DH;
        float a2 = 0.f, b2 = 0.f;
        if (q + 1 < NCHUNK) { a2 = cA[on]; b2 = cB[on]; }
        cH[o] = h;
        h = a*h + bb;
        a = a2; bb = b2; o = on;
    }
}

__global__ void scan_apply(const u16* __restrict__ delta, const u16* __restrict__ pBv,
                           const float* __restrict__ Avec, const float* __restrict__ cH,
                           u16* __restrict__ hstb) {
    const int c = blockIdx.x * blockDim.x + threadIdx.x;
    const int q = blockIdx.y;
    const int b = blockIdx.z;
    const float Ac = Avec[c];
    float h = cH[((size_t)b*NCHUNK + q)*DH + c];
    size_t base = ((size_t)b*SEQ + q*CHUNK)*DH + c;
    for (int j = 0; j < CHUNK; ++j) {
        float d = bf2f(delta[base]);
        float Abar = __expf(d * Ac);
        h = Abar*h + d * bf2f(pBv[base]);
        hstb[base] = f2bf(h);
        base += DH;
    }
}

// ---------------- host ----------------
extern "C" void kernel_launch(void* const* d_in, const int* in_sizes, int n_in,
                              void* d_out, int out_size, void* d_ws, size_t ws_size,
                              hipStream_t stream) {
    const float* x      = (const float*)d_in[0];
    const float* W1     = (const float*)d_in[1];
    const float* conv_w = (const float*)d_in[2];
    const float* conv_b = (const float*)d_in[3];
    const float* Avec   = (const float*)d_in[4];
    const float* Wb     = (const float*)d_in[5];
    const float* bb     = (const float*)d_in[6];
    const float* Wc     = (const float*)d_in[7];
    const float* bc     = (const float*)d_in[8];
    const float* Wd     = (const float*)d_in[9];
    const float* bd     = (const float*)d_in[10];
    const float* Wdelta = (const float*)d_in[11];
    const float* bdelta = (const float*)d_in[12];
    const float* W2     = (const float*)d_in[13];
    const float* Wlast  = (const float*)d_in[14];
    float* out = (float*)d_out;
    (void)in_sizes; (void)n_in; (void)out_size;

    struct Ptrs {
        u16 *sW;
        float *cA, *cB, *cH;
        u16 *xb, *x1b, *xab, *delta, *pBv, *ossb, *hstb, *zb;
        float *oss;
        size_t total;
    };
    auto layout = [&](int passes) -> Ptrs {
        Ptrs P{};
        const size_t Mp = MROWS / passes;
        const int nb = BATCH / passes;
        size_t off = 0;
        auto al = [&](size_t bytes) -> char* {
            char* p = (char*)d_ws + off; off += (bytes + 255) & ~(size_t)255; return p;
        };
        P.sW  = (u16*)al((size_t)2*DH*DMODEL*2);      // 8 MB
        P.cA  = (float*)al((size_t)nb*NCHUNK*DH*4);
        P.cB  = (float*)al((size_t)nb*NCHUNK*DH*4);
        P.cH  = (float*)al((size_t)nb*NCHUNK*DH*4);
        char* RA = al(Mp*DMODEL*2);                   // xb -> ossb
        char* RB = al(Mp*DMODEL*2);                   // x1b -> zb
        char* RC = al(Mp*DMODEL*2);                   // xab
        char* RD = al(Mp*DH*2);                       // delta -> oss (f32, same bytes)
        char* RE = al(Mp*DH*2);                       // pBv
        char* RF = al(Mp*DH*2);                       // hstb
        P.xb    = (u16*)RA; P.ossb = (u16*)RA;
        P.x1b   = (u16*)RB; P.zb   = (u16*)RB;
        P.xab   = (u16*)RC;
        P.delta = (u16*)RD; P.oss  = (float*)RD;
        P.pBv   = (u16*)RE;
        P.hstb  = (u16*)RF;
        P.total = off;
        return P;
    };

    int passes = (ws_size >= layout(1).total) ? 1 : 2;
    Ptrs P = layout(passes);
    if (ws_size < P.total) return;
    const int Mp = MROWS / passes;
    const int nb = BATCH / passes;

    const dim3 blk(256);
    auto cvt = [&](const float* s, u16* d, size_t n) {
        int n4 = (int)(n / 4);
        cvt_bf16<<<dim3((n4 + 255)/256), blk, 0, stream>>>(s, d, n4);
    };
    const dim3 gD  (DMODEL/128, Mp/128);   // 8 x 64 = 512 blocks (1-pass)
    const dim3 gDB8(2*DH/256,   Mp/256);   // 16 x 32 = 512 blocks (8-phase merged)
    u16* sW2 = P.sW + (size_t)DH*DMODEL;

    for (int p = 0; p < passes; ++p) {
        const float* x_p  = x  + (size_t)p*Mp*DMODEL;
        float*      out_p = out + (size_t)p*Mp*DMODEL;

        cvt(x_p, P.xb, (size_t)Mp*DMODEL);
        // x1 = x @ W1^T
        cvt(W1, P.sW, (size_t)DMODEL*DMODEL);
        gemm_bt<0,false><<<gD, blk, 0, stream>>>(P.xb, P.sW, DMODEL, nullptr, nullptr, 0,
                                                 nullptr, P.x1b, nullptr, nullptr, nullptr, nullptr, Mp, DMODEL);
        // xa = silu(conv3(x1))
        conv_silu8<<<dim3(Mp*DMODEL/8/256), blk, 0, stream>>>(P.x1b, conv_w, conv_b, P.xab);
        // merged: delta = softplus(xa@Wdelta^T + bdelta), pBv = xa@Wb^T + bb  (8-phase)
        cvt(Wdelta, P.sW, (size_t)DH*DMODEL);
        cvt(Wb,     sW2,  (size_t)DH*DMODEL);
        gemm8p<4><<<gDB8, dim3(512), 0, stream>>>(P.xab, P.sW, DMODEL,
                                                  P.delta, P.pBv, bdelta, bb, Mp, 2*DH);
        // chunked scan -> h_st (bf16)
        scan_chunks<<<dim3(DH/256, NCHUNK, nb), blk, 0, stream>>>(P.delta, P.pBv, Avec, P.cA, P.cB);
        scan_prefix<<<dim3(nb*DH/256), blk, 0, stream>>>(P.cA, P.cB, P.cH);
        scan_apply <<<dim3(DH/256, NCHUNK, nb), blk, 0, stream>>>(P.delta, P.pBv, Avec, P.cH, P.hstb);
        // oss = xa @ Wd^T + h_st @ Wc^T + (bd+bc)
        cvt(Wd, P.sW, (size_t)DMODEL*DMODEL);
        cvt(Wc, sW2,  (size_t)DMODEL*DH);
        gemm_bt<1,true><<<gD, blk, 0, stream>>>(P.xab, P.sW, DMODEL, P.hstb, sW2, DH,
                                                P.oss, P.ossb, nullptr, bd, bc, nullptr, Mp, DMODEL);
        // z = oss * silu(oss @ W2^T)
        cvt(W2, P.sW, (size_t)DMODEL*DMODEL);
        gemm_bt<2,false><<<gD, blk, 0, stream>>>(P.ossb, P.sW, DMODEL, nullptr, nullptr, 0,
                                                 nullptr, P.zb, nullptr, nullptr, nullptr, P.oss, Mp, DMODEL);
        // out = oss + z @ Wlast^T
        cvt(Wlast, P.sW, (size_t)DMODEL*DMODEL);
        gemm_bt<3,false><<<gD, blk, 0, stream>>>(P.zb, P.sW, DMODEL, nullptr, nullptr, 0,
                                                 out_p, nullptr, nullptr, nullptr, nullptr, P.oss, Mp, DMODEL);
    }
}

// Round 15
// 306.406 us; speedup vs baseline: 1.1087x; 1.1087x over previous
//
#include <hip/hip_runtime.h>
#include <cstdint>
#include <cstddef>

#define DMODEL 1024
#define DH 2048
#define BATCH 2
#define SEQ 4096
#define MROWS (BATCH*SEQ)    // 8192
#define CHUNK 64
#define NCHUNK (SEQ/CHUNK)   // 64

typedef unsigned short u16;
typedef __attribute__((ext_vector_type(8))) short bf16x8;
typedef __attribute__((ext_vector_type(4))) float f32x4;

__device__ __forceinline__ u16 f2bf(float f) {
    union { float f; unsigned u; } v; v.f = f;
    unsigned r = v.u + 0x7FFFu + ((v.u >> 16) & 1u);
    return (u16)(r >> 16);
}
__device__ __forceinline__ float bf2f(u16 h) {
    union { unsigned u; float f; } v; v.u = ((unsigned)h) << 16; return v.f;
}

__device__ __forceinline__ float softplus_fast(float x) {
    if (x < -4.f) return __expf(x);
    return (x > 0.f) ? (x + log1pf(__expf(-x))) : log1pf(__expf(x));
}
__device__ __forceinline__ float silu_fast(float v) {
    return v * __fdividef(1.f, 1.f + __expf(-v));
}

// ---------------- f32 -> bf16, 4 elems/thread ----------------
__global__ void cvt_bf16(const float* __restrict__ src, u16* __restrict__ dst, int n4) {
    int i = blockIdx.x * blockDim.x + threadIdx.x;
    if (i >= n4) return;
    const float4 v = reinterpret_cast<const float4*>(src)[i];
    ushort4 o;
    o.x = f2bf(v.x); o.y = f2bf(v.y); o.z = f2bf(v.z); o.w = f2bf(v.w);
    reinterpret_cast<ushort4*>(dst)[i] = o;
}

// ---------------- GEMM: C[M,N] = A[M,K] @ B[N,K]^T  (bf16 in, f32 acc) ----------------
// R15 = R13 verified structure (the R14 8-phase port regressed; reverted per two-lane
// discipline). 128x128 tile, BK=64, 256 thr, single-buffered 32 KB LDS,
// __launch_bounds__(256,4) -> 4 blocks/CU (16 waves/CU, m114 overlap). Coalesced LDS
// epilogue (R12). XOR swizzle both sides (rule 21); 8x8 supertile XCD raster (R9).
// NEW: oss kept bf16-only -> EP1 eliminated (EP0 takes 2 biases); EP2/EP3 aux is bf16.
// EP 0: Cb = bf16(acc + b1 + b2)
// EP 2: Cb = bf16(aux * silu(acc))             (gate; aux bf16)
// EP 3: C  = aux + acc                         (final residual, f32 out; aux bf16)
// EP 4: N=2*DH block-uniform split: n0<DH -> Cb=bf16(softplus(acc+b1)) else Cb2=bf16(acc+b2)
__device__ __forceinline__ void gload_lds16(const void* g, void* l) {
    __builtin_amdgcn_global_load_lds(
        (const __attribute__((address_space(1))) void*)g,
        (__attribute__((address_space(3))) void*)l,
        16, 0, 0);
}

template<int EP, bool TWOK>
__global__ __launch_bounds__(256, 4) void gemm_bt(
    const u16* __restrict__ A1, const u16* __restrict__ B1, int K1,
    const u16* __restrict__ A2, const u16* __restrict__ B2, int K2,
    float* __restrict__ C, u16* __restrict__ Cb, u16* __restrict__ Cb2,
    const float* __restrict__ bias, const float* __restrict__ bias2,
    const u16* __restrict__ aux,
    int M, int N)
{
    __shared__ __align__(16) char smem[32768];
    u16* As = (u16*)smem;              // [128 rows][8 chunks of 16B], swizzled
    u16* Bs = (u16*)(smem + 16384);
    float* ep = (float*)smem;          // epilogue scratch [32][132] f32

    const int tid = threadIdx.x;

    // 8x8 supertile rasterization in XCD-contiguous chunks (R9; bijective for our grids)
    const int nwg = gridDim.x * gridDim.y;
    int wg = blockIdx.y * gridDim.x + blockIdx.x;
    wg = (wg & 7) * (nwg >> 3) + (wg >> 3);
    const int stile = wg >> 6;
    const int t64   = wg & 63;
    const int nSn   = gridDim.x >> 3;
    const int sm = (nSn > 0) ? stile / nSn : stile;
    const int sn = (nSn > 0) ? stile - sm * nSn : 0;
    const int m0 = (sm * 8 + (t64 >> 3)) * 128;
    const int n0 = (sn * 8 + (t64 & 7)) * 128;

    const int wave = tid >> 6, lane = tid & 63;
    const int wr = (wave >> 1) * 64;   // 2x2 wave grid, 64x64 per wave
    const int wc = (wave & 1) * 64;
    const int fr = lane & 15, fq = lane >> 4;

    f32x4 acc[4][4];
    #pragma unroll
    for (int m = 0; m < 4; m++)
        #pragma unroll
        for (int n = 0; n < 4; n++) acc[m][n] = f32x4{0.f, 0.f, 0.f, 0.f};

    const int nt1 = K1 >> 6;
    const int nt  = TWOK ? nt1 + (K2 >> 6) : nt1;

    for (int t = 0; t < nt; ++t) {
        const u16* A = A1; const u16* B = B1; int K = K1; int k0 = t << 6;
        if (TWOK && t >= nt1) { A = A2; B = B2; K = K2; k0 = (t - nt1) << 6; }
        // stage 16 KB each of A,B: 1024 granules of 16B per matrix, 4/thread
        #pragma unroll
        for (int i = 0; i < 4; ++i) {
            const int g = i*256 + tid;
            const int r = g >> 3;
            const int ch = (g & 7) ^ (r & 7);       // pre-swizzled source chunk
            gload_lds16(A + (size_t)(m0 + r)*K + (k0 + ch*8), (char*)As + (size_t)g*16);
            gload_lds16(B + (size_t)(n0 + r)*K + (k0 + ch*8), (char*)Bs + (size_t)g*16);
        }
        __syncthreads();   // compiler drains vmcnt before barrier (m97 structure)

        #pragma unroll
        for (int kk = 0; kk < 2; ++kk) {
            bf16x8 af[4], bfr[4];
            #pragma unroll
            for (int m = 0; m < 4; m++) {
                const int r = wr + m*16 + fr;
                af[m] = *reinterpret_cast<const bf16x8*>(
                    (const char*)As + r*128 + (((kk*4 + fq) ^ (r & 7)) * 16));
            }
            #pragma unroll
            for (int n = 0; n < 4; n++) {
                const int r = wc + n*16 + fr;
                bfr[n] = *reinterpret_cast<const bf16x8*>(
                    (const char*)Bs + r*128 + (((kk*4 + fq) ^ (r & 7)) * 16));
            }
            #pragma unroll
            for (int m = 0; m < 4; m++)
                #pragma unroll
                for (int n = 0; n < 4; n++)
                    acc[m][n] = __builtin_amdgcn_mfma_f32_16x16x32_bf16(af[m], bfr[n], acc[m][n], 0, 0, 0);
        }
        __syncthreads();
    }

    // ---------- coalesced epilogue: 4 chunks of 32 rows through LDS ----------
    const bool isDelta = (EP == 4) ? (n0 < DH) : false;
    #pragma unroll
    for (int c = 0; c < 4; ++c) {
        if ((wave >> 1) == (c >> 1)) {   // the 2 waves owning rows [c*32, c*32+32)
            const int mb = (c & 1) * 2;  // fragment pair {mb, mb+1}
            #pragma unroll
            for (int mi = 0; mi < 2; mi++) {
                #pragma unroll
                for (int n = 0; n < 4; n++) {
                    const int col = wc + n*16 + fr;
                    #pragma unroll
                    for (int j = 0; j < 4; j++)
                        ep[(mi*16 + fq*4 + j)*132 + col] = acc[mb + mi][n][j];
                }
            }
        }
        __syncthreads();
        #pragma unroll
        for (int p = 0; p < 4; ++p) {
            const int idx = p*256 + tid;        // 1024 float4 per chunk
            const int row = idx >> 5, c4 = idx & 31;
            float4 v = *reinterpret_cast<const float4*>(&ep[row*132 + c4*4]);
            const int rg   = m0 + c*32 + row;
            const int colg = n0 + c4*4;
            if constexpr (EP == 4) {
                const int cc = isDelta ? colg : (colg - DH);
                const float4 bv = *reinterpret_cast<const float4*>(
                    (isDelta ? bias : bias2) + cc);
                ushort4 o;
                if (isDelta) {
                    o.x = f2bf(softplus_fast(v.x + bv.x));
                    o.y = f2bf(softplus_fast(v.y + bv.y));
                    o.z = f2bf(softplus_fast(v.z + bv.z));
                    o.w = f2bf(softplus_fast(v.w + bv.w));
                } else {
                    o.x = f2bf(v.x + bv.x); o.y = f2bf(v.y + bv.y);
                    o.z = f2bf(v.z + bv.z); o.w = f2bf(v.w + bv.w);
                }
                *reinterpret_cast<ushort4*>((isDelta ? Cb : Cb2) + (size_t)rg*DH + cc) = o;
            } else {
                if (bias) {
                    const float4 b1 = *reinterpret_cast<const float4*>(bias + colg);
                    v.x += b1.x; v.y += b1.y; v.z += b1.z; v.w += b1.w;
                }
                if (bias2) {
                    const float4 b2 = *reinterpret_cast<const float4*>(bias2 + colg);
                    v.x += b2.x; v.y += b2.y; v.z += b2.z; v.w += b2.w;
                }
                const size_t gidx = (size_t)rg * N + colg;
                if constexpr (EP == 0) {
                    ushort4 o = { f2bf(v.x), f2bf(v.y), f2bf(v.z), f2bf(v.w) };
                    *reinterpret_cast<ushort4*>(Cb + gidx) = o;
                } else if constexpr (EP == 2) {
                    const ushort4 ab = *reinterpret_cast<const ushort4*>(aux + gidx);
                    ushort4 o = { f2bf(bf2f(ab.x) * silu_fast(v.x)),
                                  f2bf(bf2f(ab.y) * silu_fast(v.y)),
                                  f2bf(bf2f(ab.z) * silu_fast(v.z)),
                                  f2bf(bf2f(ab.w) * silu_fast(v.w)) };
                    *reinterpret_cast<ushort4*>(Cb + gidx) = o;
                } else {   // EP 3
                    const ushort4 ab = *reinterpret_cast<const ushort4*>(aux + gidx);
                    float4 o = { bf2f(ab.x) + v.x, bf2f(ab.y) + v.y,
                                 bf2f(ab.z) + v.z, bf2f(ab.w) + v.w };
                    *reinterpret_cast<float4*>(C + gidx) = o;
                }
            }
        }
        __syncthreads();
    }
}

// ---------------- depthwise conv3 (pad 1, per seq of 4096) + silu, bf16x8 ----------------
__global__ void conv_silu8(const u16* __restrict__ x1, const float* __restrict__ cw,
                           const float* __restrict__ cb, u16* __restrict__ xab) {
    int t = blockIdx.x * blockDim.x + threadIdx.x;
    int c8  = t & (DMODEL/8 - 1);
    int row = t >> 7;
    int l = row & (SEQ - 1);
    const int c0 = c8 * 8;
    const size_t i0 = (size_t)row * DMODEL + c0;
    bf16x8 v0 = *reinterpret_cast<const bf16x8*>(x1 + i0);
    bf16x8 vm = {}; if (l > 0)       vm = *reinterpret_cast<const bf16x8*>(x1 + i0 - DMODEL);
    bf16x8 vp = {}; if (l < SEQ - 1) vp = *reinterpret_cast<const bf16x8*>(x1 + i0 + DMODEL);
    if (l == 0)       vm = bf16x8{};
    if (l == SEQ - 1) vp = bf16x8{};
    bf16x8 o;
    #pragma unroll
    for (int j = 0; j < 8; ++j) {
        const int c = c0 + j;
        float v = cw[c*3+0]*bf2f((u16)vm[j]) + cw[c*3+1]*bf2f((u16)v0[j])
                + cw[c*3+2]*bf2f((u16)vp[j]) + cb[c];
        o[j] = (short)f2bf(silu_fast(v));
    }
    *reinterpret_cast<bf16x8*>(xab + i0) = o;
}

// ---------------- SSM chunked scan (batch in grid.z) ----------------
__global__ void scan_chunks(const u16* __restrict__ delta, const u16* __restrict__ pBv,
                            const float* __restrict__ Avec,
                            float* __restrict__ cA, float* __restrict__ cB) {
    const int c = blockIdx.x * blockDim.x + threadIdx.x;
    const int q = blockIdx.y;
    const int b = blockIdx.z;
    const float Ac = Avec[c];
    float hA = 1.f, hB = 0.f;
    size_t base = ((size_t)b*SEQ + q*CHUNK)*DH + c;
    for (int j = 0; j < CHUNK; ++j) {
        float d = bf2f(delta[base]);
        float Abar = __expf(d * Ac);
        hA *= Abar;
        hB = Abar*hB + d * bf2f(pBv[base]);
        base += DH;
    }
    size_t o = ((size_t)b*NCHUNK + q)*DH + c;
    cA[o] = hA; cB[o] = hB;
}

__global__ void scan_prefix(const float* __restrict__ cA, const float* __restrict__ cB,
                            float* __restrict__ cH) {
    const int t = blockIdx.x * blockDim.x + threadIdx.x;
    const int b = t >> 11;
    const int c = t & (DH - 1);
    float h = 0.f;
    size_t o = ((size_t)b*NCHUNK)*DH + c;
    float a = cA[o], bb = cB[o];
    for (int q = 0; q < NCHUNK; ++q) {
        const size_t on = o + DH;
        float a2 = 0.f, b2 = 0.f;
        if (q + 1 < NCHUNK) { a2 = cA[on]; b2 = cB[on]; }
        cH[o] = h;
        h = a*h + bb;
        a = a2; bb = b2; o = on;
    }
}

__global__ void scan_apply(const u16* __restrict__ delta, const u16* __restrict__ pBv,
                           const float* __restrict__ Avec, const float* __restrict__ cH,
                           u16* __restrict__ hstb) {
    const int c = blockIdx.x * blockDim.x + threadIdx.x;
    const int q = blockIdx.y;
    const int b = blockIdx.z;
    const float Ac = Avec[c];
    float h = cH[((size_t)b*NCHUNK + q)*DH + c];
    size_t base = ((size_t)b*SEQ + q*CHUNK)*DH + c;
    for (int j = 0; j < CHUNK; ++j) {
        float d = bf2f(delta[base]);
        float Abar = __expf(d * Ac);
        h = Abar*h + d * bf2f(pBv[base]);
        hstb[base] = f2bf(h);
        base += DH;
    }
}

// ---------------- host ----------------
extern "C" void kernel_launch(void* const* d_in, const int* in_sizes, int n_in,
                              void* d_out, int out_size, void* d_ws, size_t ws_size,
                              hipStream_t stream) {
    const float* x      = (const float*)d_in[0];
    const float* W1     = (const float*)d_in[1];
    const float* conv_w = (const float*)d_in[2];
    const float* conv_b = (const float*)d_in[3];
    const float* Avec   = (const float*)d_in[4];
    const float* Wb     = (const float*)d_in[5];
    const float* bb     = (const float*)d_in[6];
    const float* Wc     = (const float*)d_in[7];
    const float* bc     = (const float*)d_in[8];
    const float* Wd     = (const float*)d_in[9];
    const float* bd     = (const float*)d_in[10];
    const float* Wdelta = (const float*)d_in[11];
    const float* bdelta = (const float*)d_in[12];
    const float* W2     = (const float*)d_in[13];
    const float* Wlast  = (const float*)d_in[14];
    float* out = (float*)d_out;
    (void)in_sizes; (void)n_in; (void)out_size;

    struct Ptrs {
        u16 *sW;
        float *cA, *cB, *cH;
        u16 *xb, *x1b, *xab, *delta, *pBv, *ossb, *hstb, *zb;
        size_t total;
    };
    auto layout = [&](int passes) -> Ptrs {
        Ptrs P{};
        const size_t Mp = MROWS / passes;
        const int nb = BATCH / passes;
        size_t off = 0;
        auto al = [&](size_t bytes) -> char* {
            char* p = (char*)d_ws + off; off += (bytes + 255) & ~(size_t)255; return p;
        };
        P.sW  = (u16*)al((size_t)2*DH*DMODEL*2);      // 8 MB
        P.cA  = (float*)al((size_t)nb*NCHUNK*DH*4);
        P.cB  = (float*)al((size_t)nb*NCHUNK*DH*4);
        P.cH  = (float*)al((size_t)nb*NCHUNK*DH*4);
        char* RA = al(Mp*DMODEL*2);                   // xb -> ossb
        char* RB = al(Mp*DMODEL*2);                   // x1b -> zb
        char* RC = al(Mp*DMODEL*2);                   // xab
        char* RD = al(Mp*DH*2);                       // delta
        char* RE = al(Mp*DH*2);                       // pBv
        char* RF = al(Mp*DH*2);                       // hstb
        P.xb    = (u16*)RA; P.ossb = (u16*)RA;
        P.x1b   = (u16*)RB; P.zb   = (u16*)RB;
        P.xab   = (u16*)RC;
        P.delta = (u16*)RD;
        P.pBv   = (u16*)RE;
        P.hstb  = (u16*)RF;
        P.total = off;
        return P;
    };

    int passes = (ws_size >= layout(1).total) ? 1 : 2;
    Ptrs P = layout(passes);
    if (ws_size < P.total) return;
    const int Mp = MROWS / passes;
    const int nb = BATCH / passes;

    const dim3 blk(256);
    auto cvt = [&](const float* s, u16* d, size_t n) {
        int n4 = (int)(n / 4);
        cvt_bf16<<<dim3((n4 + 255)/256), blk, 0, stream>>>(s, d, n4);
    };
    const dim3 gD (DMODEL/128, Mp/128);   // 8 x 64 = 512 blocks (1-pass)
    const dim3 gDB(2*DH/128,   Mp/128);   // 32 x 64 = 2048 blocks (merged delta|pBv)
    u16* sW2 = P.sW + (size_t)DH*DMODEL;

    for (int p = 0; p < passes; ++p) {
        const float* x_p  = x  + (size_t)p*Mp*DMODEL;
        float*      out_p = out + (size_t)p*Mp*DMODEL;

        cvt(x_p, P.xb, (size_t)Mp*DMODEL);
        // x1 = x @ W1^T
        cvt(W1, P.sW, (size_t)DMODEL*DMODEL);
        gemm_bt<0,false><<<gD, blk, 0, stream>>>(P.xb, P.sW, DMODEL, nullptr, nullptr, 0,
                                                 nullptr, P.x1b, nullptr, nullptr, nullptr, nullptr, Mp, DMODEL);
        // xa = silu(conv3(x1))
        conv_silu8<<<dim3(Mp*DMODEL/8/256), blk, 0, stream>>>(P.x1b, conv_w, conv_b, P.xab);
        // merged: delta = softplus(xa@Wdelta^T + bdelta), pBv = xa@Wb^T + bb
        cvt(Wdelta, P.sW, (size_t)DH*DMODEL);
        cvt(Wb,     sW2,  (size_t)DH*DMODEL);
        gemm_bt<4,false><<<gDB, blk, 0, stream>>>(P.xab, P.sW, DMODEL, nullptr, nullptr, 0,
                                                  nullptr, P.delta, P.pBv, bdelta, bb, nullptr, Mp, 2*DH);
        // chunked scan -> h_st (bf16)
        scan_chunks<<<dim3(DH/256, NCHUNK, nb), blk, 0, stream>>>(P.delta, P.pBv, Avec, P.cA, P.cB);
        scan_prefix<<<dim3(nb*DH/256), blk, 0, stream>>>(P.cA, P.cB, P.cH);
        scan_apply <<<dim3(DH/256, NCHUNK, nb), blk, 0, stream>>>(P.delta, P.pBv, Avec, P.cH, P.hstb);
        // ossb = bf16(xa @ Wd^T + h_st @ Wc^T + bd + bc)   (bf16-only now)
        cvt(Wd, P.sW, (size_t)DMODEL*DMODEL);
        cvt(Wc, sW2,  (size_t)DMODEL*DH);
        gemm_bt<0,true><<<gD, blk, 0, stream>>>(P.xab, P.sW, DMODEL, P.hstb, sW2, DH,
                                                nullptr, P.ossb, nullptr, bd, bc, nullptr, Mp, DMODEL);
        // z = ossb * silu(ossb @ W2^T)
        cvt(W2, P.sW, (size_t)DMODEL*DMODEL);
        gemm_bt<2,false><<<gD, blk, 0, stream>>>(P.ossb, P.sW, DMODEL, nullptr, nullptr, 0,
                                                 nullptr, P.zb, nullptr, nullptr, nullptr, P.ossb, Mp, DMODEL);
        // out = ossb + z @ Wlast^T
        cvt(Wlast, P.sW, (size_t)DMODEL*DMODEL);
        gemm_bt<3,false><<<gD, blk, 0, stream>>>(P.zb, P.sW, DMODEL, nullptr, nullptr, 0,
                                                 out_p, nullptr, nullptr, nullptr, nullptr, P.ossb, Mp, DMODEL);
    }
}

// Round 16
// 298.746 us; speedup vs baseline: 1.1371x; 1.0256x over previous
//
#include <hip/hip_runtime.h>
#include <cstdint>
#include <cstddef>

#define DMODEL 1024
#define DH 2048
#define BATCH 2
#define SEQ 4096
#define MROWS (BATCH*SEQ)    // 8192
#define CHUNK 64
#define NCHUNK (SEQ/CHUNK)   // 64

typedef unsigned short u16;
typedef unsigned int u32;
typedef __attribute__((ext_vector_type(8))) short bf16x8;
typedef __attribute__((ext_vector_type(4))) float f32x4;

__device__ __forceinline__ u16 f2bf(float f) {
    union { float f; unsigned u; } v; v.f = f;
    unsigned r = v.u + 0x7FFFu + ((v.u >> 16) & 1u);
    return (u16)(r >> 16);
}
__device__ __forceinline__ float bf2f(u16 h) {
    union { unsigned u; float f; } v; v.u = ((unsigned)h) << 16; return v.f;
}

__device__ __forceinline__ float softplus_fast(float x) {
    if (x < -4.f) return __expf(x);
    return (x > 0.f) ? (x + log1pf(__expf(-x))) : log1pf(__expf(x));
}
__device__ __forceinline__ float silu_fast(float v) {
    return v * __fdividef(1.f, 1.f + __expf(-v));
}

// ---------------- f32 -> bf16, 4 elems/thread (single buffer) ----------------
__global__ void cvt_bf16(const float* __restrict__ src, u16* __restrict__ dst, int n4) {
    int i = blockIdx.x * blockDim.x + threadIdx.x;
    if (i >= n4) return;
    const float4 v = reinterpret_cast<const float4*>(src)[i];
    ushort4 o;
    o.x = f2bf(v.x); o.y = f2bf(v.y); o.z = f2bf(v.z); o.w = f2bf(v.w);
    reinterpret_cast<ushort4*>(dst)[i] = o;
}

// ---------------- fused multi-buffer f32 -> bf16 (all weights, one launch) ----------------
struct CvtArgs {
    const float* src[7];
    u16* dst[7];
    unsigned cum[8];   // cumulative float4 counts; cum[7] = total
};
__global__ void cvt_multi(CvtArgs a) {
    const unsigned i = blockIdx.x * blockDim.x + threadIdx.x;
    if (i >= a.cum[7]) return;
    int s = 0;
    while (i >= a.cum[s+1]) ++s;       // <=7 uniform-ish steps
    const unsigned off = i - a.cum[s];
    const float4 v = reinterpret_cast<const float4*>(a.src[s])[off];
    ushort4 o;
    o.x = f2bf(v.x); o.y = f2bf(v.y); o.z = f2bf(v.z); o.w = f2bf(v.w);
    reinterpret_cast<ushort4*>(a.dst[s])[off] = o;
}

// ---------------- GEMM: C[M,N] = A[M,K] @ B[N,K]^T  (bf16 in, f32 acc) ----------------
// R16 = R13/R15 verified structure; LDS grown 32->40 KB (still exactly 4 blocks/CU:
// 160/40=4) so the coalesced epilogue runs in 2 rounds of [64][132] f32 instead of 4
// rounds of [32][132] (halves epilogue barriers). Mainloop unchanged: 128x128 tile,
// BK=64, 256 thr, single-buffered 32 KB, gload_lds width-16, XOR swizzle both sides,
// 8x8 supertile XCD raster.
// EP 0: Cb = bf16(acc + b1 [+ b2])
// EP 2: Cb = bf16(aux * silu(acc))             (gate; aux bf16)
// EP 3: C  = aux + acc                         (final residual, f32 out; aux bf16)
// EP 4: N=2*DH split: n0<DH -> Cb=bf16(softplus(acc+b1)) else Cb2=bf16(acc+b2)
__device__ __forceinline__ void gload_lds16(const void* g, void* l) {
    __builtin_amdgcn_global_load_lds(
        (const __attribute__((address_space(1))) void*)g,
        (__attribute__((address_space(3))) void*)l,
        16, 0, 0);
}

template<int EP, bool TWOK>
__global__ __launch_bounds__(256, 4) void gemm_bt(
    const u16* __restrict__ A1, const u16* __restrict__ B1, int K1,
    const u16* __restrict__ A2, const u16* __restrict__ B2, int K2,
    float* __restrict__ C, u16* __restrict__ Cb, u16* __restrict__ Cb2,
    const float* __restrict__ bias, const float* __restrict__ bias2,
    const u16* __restrict__ aux,
    int M, int N)
{
    __shared__ __align__(16) char smem[40960];
    u16* As = (u16*)smem;              // [128 rows][8 chunks of 16B], swizzled
    u16* Bs = (u16*)(smem + 16384);
    float* ep = (float*)smem;          // epilogue scratch [64][132] f32 (33.8 KB)

    const int tid = threadIdx.x;

    // 8x8 supertile rasterization in XCD-contiguous chunks (bijective for our grids)
    const int nwg = gridDim.x * gridDim.y;
    int wg = blockIdx.y * gridDim.x + blockIdx.x;
    wg = (wg & 7) * (nwg >> 3) + (wg >> 3);
    const int stile = wg >> 6;
    const int t64   = wg & 63;
    const int nSn   = gridDim.x >> 3;
    const int sm = (nSn > 0) ? stile / nSn : stile;
    const int sn = (nSn > 0) ? stile - sm * nSn : 0;
    const int m0 = (sm * 8 + (t64 >> 3)) * 128;
    const int n0 = (sn * 8 + (t64 & 7)) * 128;

    const int wave = tid >> 6, lane = tid & 63;
    const int wr = (wave >> 1) * 64;   // 2x2 wave grid, 64x64 per wave
    const int wc = (wave & 1) * 64;
    const int fr = lane & 15, fq = lane >> 4;

    f32x4 acc[4][4];
    #pragma unroll
    for (int m = 0; m < 4; m++)
        #pragma unroll
        for (int n = 0; n < 4; n++) acc[m][n] = f32x4{0.f, 0.f, 0.f, 0.f};

    const int nt1 = K1 >> 6;
    const int nt  = TWOK ? nt1 + (K2 >> 6) : nt1;

    for (int t = 0; t < nt; ++t) {
        const u16* A = A1; const u16* B = B1; int K = K1; int k0 = t << 6;
        if (TWOK && t >= nt1) { A = A2; B = B2; K = K2; k0 = (t - nt1) << 6; }
        #pragma unroll
        for (int i = 0; i < 4; ++i) {
            const int g = i*256 + tid;
            const int r = g >> 3;
            const int ch = (g & 7) ^ (r & 7);       // pre-swizzled source chunk
            gload_lds16(A + (size_t)(m0 + r)*K + (k0 + ch*8), (char*)As + (size_t)g*16);
            gload_lds16(B + (size_t)(n0 + r)*K + (k0 + ch*8), (char*)Bs + (size_t)g*16);
        }
        __syncthreads();

        #pragma unroll
        for (int kk = 0; kk < 2; ++kk) {
            bf16x8 af[4], bfr[4];
            #pragma unroll
            for (int m = 0; m < 4; m++) {
                const int r = wr + m*16 + fr;
                af[m] = *reinterpret_cast<const bf16x8*>(
                    (const char*)As + r*128 + (((kk*4 + fq) ^ (r & 7)) * 16));
            }
            #pragma unroll
            for (int n = 0; n < 4; n++) {
                const int r = wc + n*16 + fr;
                bfr[n] = *reinterpret_cast<const bf16x8*>(
                    (const char*)Bs + r*128 + (((kk*4 + fq) ^ (r & 7)) * 16));
            }
            #pragma unroll
            for (int m = 0; m < 4; m++)
                #pragma unroll
                for (int n = 0; n < 4; n++)
                    acc[m][n] = __builtin_amdgcn_mfma_f32_16x16x32_bf16(af[m], bfr[n], acc[m][n], 0, 0, 0);
        }
        __syncthreads();
    }

    // ---------- coalesced epilogue: 2 rounds of 64 rows through LDS ----------
    const bool isDelta = (EP == 4) ? (n0 < DH) : false;
    #pragma unroll
    for (int c = 0; c < 2; ++c) {
        if ((wave >> 1) == c) {          // the 2 waves owning rows [c*64, c*64+64)
            #pragma unroll
            for (int m = 0; m < 4; m++)
                #pragma unroll
                for (int n = 0; n < 4; n++) {
                    const int col = wc + n*16 + fr;
                    #pragma unroll
                    for (int j = 0; j < 4; j++)
                        ep[(m*16 + fq*4 + j)*132 + col] = acc[m][n][j];
                }
        }
        __syncthreads();
        #pragma unroll
        for (int p = 0; p < 8; ++p) {
            const int idx = p*256 + tid;        // 2048 float4 per round
            const int row = idx >> 5, c4 = idx & 31;
            float4 v = *reinterpret_cast<const float4*>(&ep[row*132 + c4*4]);
            const int rg   = m0 + c*64 + row;
            const int colg = n0 + c4*4;
            if constexpr (EP == 4) {
                const int cc = isDelta ? colg : (colg - DH);
                const float4 bv = *reinterpret_cast<const float4*>(
                    (isDelta ? bias : bias2) + cc);
                ushort4 o;
                if (isDelta) {
                    o.x = f2bf(softplus_fast(v.x + bv.x));
                    o.y = f2bf(softplus_fast(v.y + bv.y));
                    o.z = f2bf(softplus_fast(v.z + bv.z));
                    o.w = f2bf(softplus_fast(v.w + bv.w));
                } else {
                    o.x = f2bf(v.x + bv.x); o.y = f2bf(v.y + bv.y);
                    o.z = f2bf(v.z + bv.z); o.w = f2bf(v.w + bv.w);
                }
                *reinterpret_cast<ushort4*>((isDelta ? Cb : Cb2) + (size_t)rg*DH + cc) = o;
            } else {
                if (bias) {
                    const float4 b1 = *reinterpret_cast<const float4*>(bias + colg);
                    v.x += b1.x; v.y += b1.y; v.z += b1.z; v.w += b1.w;
                }
                if (bias2) {
                    const float4 b2 = *reinterpret_cast<const float4*>(bias2 + colg);
                    v.x += b2.x; v.y += b2.y; v.z += b2.z; v.w += b2.w;
                }
                const size_t gidx = (size_t)rg * N + colg;
                if constexpr (EP == 0) {
                    ushort4 o = { f2bf(v.x), f2bf(v.y), f2bf(v.z), f2bf(v.w) };
                    *reinterpret_cast<ushort4*>(Cb + gidx) = o;
                } else if constexpr (EP == 2) {
                    const ushort4 ab = *reinterpret_cast<const ushort4*>(aux + gidx);
                    ushort4 o = { f2bf(bf2f(ab.x) * silu_fast(v.x)),
                                  f2bf(bf2f(ab.y) * silu_fast(v.y)),
                                  f2bf(bf2f(ab.z) * silu_fast(v.z)),
                                  f2bf(bf2f(ab.w) * silu_fast(v.w)) };
                    *reinterpret_cast<ushort4*>(Cb + gidx) = o;
                } else {   // EP 3
                    const ushort4 ab = *reinterpret_cast<const ushort4*>(aux + gidx);
                    float4 o = { bf2f(ab.x) + v.x, bf2f(ab.y) + v.y,
                                 bf2f(ab.z) + v.z, bf2f(ab.w) + v.w };
                    *reinterpret_cast<float4*>(C + gidx) = o;
                }
            }
        }
        __syncthreads();
    }
}

// ---------------- depthwise conv3 (pad 1, per seq of 4096) + silu, bf16x8 ----------------
__global__ void conv_silu8(const u16* __restrict__ x1, const float* __restrict__ cw,
                           const float* __restrict__ cb, u16* __restrict__ xab) {
    int t = blockIdx.x * blockDim.x + threadIdx.x;
    int c8  = t & (DMODEL/8 - 1);
    int row = t >> 7;
    int l = row & (SEQ - 1);
    const int c0 = c8 * 8;
    const size_t i0 = (size_t)row * DMODEL + c0;
    bf16x8 v0 = *reinterpret_cast<const bf16x8*>(x1 + i0);
    bf16x8 vm = {}; if (l > 0)       vm = *reinterpret_cast<const bf16x8*>(x1 + i0 - DMODEL);
    bf16x8 vp = {}; if (l < SEQ - 1) vp = *reinterpret_cast<const bf16x8*>(x1 + i0 + DMODEL);
    if (l == 0)       vm = bf16x8{};
    if (l == SEQ - 1) vp = bf16x8{};
    bf16x8 o;
    #pragma unroll
    for (int j = 0; j < 8; ++j) {
        const int c = c0 + j;
        float v = cw[c*3+0]*bf2f((u16)vm[j]) + cw[c*3+1]*bf2f((u16)v0[j])
                + cw[c*3+2]*bf2f((u16)vp[j]) + cb[c];
        o[j] = (short)f2bf(silu_fast(v));
    }
    *reinterpret_cast<bf16x8*>(xab + i0) = o;
}

// ---------------- SSM chunked scan: 2 channels/thread via u32 loads ----------------
__global__ void scan_chunks(const u16* __restrict__ delta, const u16* __restrict__ pBv,
                            const float* __restrict__ Avec,
                            float* __restrict__ cA, float* __restrict__ cB) {
    const int c = (blockIdx.x * blockDim.x + threadIdx.x) * 2;
    const int q = blockIdx.y;
    const int b = blockIdx.z;
    const float A0 = Avec[c], A1 = Avec[c+1];
    float hA0 = 1.f, hB0 = 0.f, hA1 = 1.f, hB1 = 0.f;
    size_t base = ((size_t)b*SEQ + q*CHUNK)*DH + c;
    for (int j = 0; j < CHUNK; ++j) {
        const u32 du = *reinterpret_cast<const u32*>(delta + base);
        const u32 pu = *reinterpret_cast<const u32*>(pBv + base);
        const float d0 = bf2f((u16)(du & 0xFFFF)), d1 = bf2f((u16)(du >> 16));
        const float p0 = bf2f((u16)(pu & 0xFFFF)), p1 = bf2f((u16)(pu >> 16));
        const float a0 = __expf(d0 * A0), a1 = __expf(d1 * A1);
        hA0 *= a0; hB0 = a0*hB0 + d0*p0;
        hA1 *= a1; hB1 = a1*hB1 + d1*p1;
        base += DH;
    }
    size_t o = ((size_t)b*NCHUNK + q)*DH + c;
    cA[o] = hA0; cA[o+1] = hA1;
    cB[o] = hB0; cB[o+1] = hB1;
}

__global__ void scan_prefix(const float* __restrict__ cA, const float* __restrict__ cB,
                            float* __restrict__ cH) {
    const int t = blockIdx.x * blockDim.x + threadIdx.x;
    const int b = t >> 11;
    const int c = t & (DH - 1);
    float h = 0.f;
    size_t o = ((size_t)b*NCHUNK)*DH + c;
    float a = cA[o], bb = cB[o];
    for (int q = 0; q < NCHUNK; ++q) {
        const size_t on = o + DH;
        float a2 = 0.f, b2 = 0.f;
        if (q + 1 < NCHUNK) { a2 = cA[on]; b2 = cB[on]; }
        cH[o] = h;
        h = a*h + bb;
        a = a2; bb = b2; o = on;
    }
}

__global__ void scan_apply(const u16* __restrict__ delta, const u16* __restrict__ pBv,
                           const float* __restrict__ Avec, const float* __restrict__ cH,
                           u16* __restrict__ hstb) {
    const int c = (blockIdx.x * blockDim.x + threadIdx.x) * 2;
    const int q = blockIdx.y;
    const int b = blockIdx.z;
    const float A0 = Avec[c], A1 = Avec[c+1];
    const size_t oh = ((size_t)b*NCHUNK + q)*DH + c;
    float h0 = cH[oh], h1 = cH[oh+1];
    size_t base = ((size_t)b*SEQ + q*CHUNK)*DH + c;
    for (int j = 0; j < CHUNK; ++j) {
        const u32 du = *reinterpret_cast<const u32*>(delta + base);
        const u32 pu = *reinterpret_cast<const u32*>(pBv + base);
        const float d0 = bf2f((u16)(du & 0xFFFF)), d1 = bf2f((u16)(du >> 16));
        const float p0 = bf2f((u16)(pu & 0xFFFF)), p1 = bf2f((u16)(pu >> 16));
        const float a0 = __expf(d0 * A0), a1 = __expf(d1 * A1);
        h0 = a0*h0 + d0*p0;
        h1 = a1*h1 + d1*p1;
        const u32 hv = (u32)f2bf(h0) | ((u32)f2bf(h1) << 16);
        *reinterpret_cast<u32*>(hstb + base) = hv;
        base += DH;
    }
}

// ---------------- host ----------------
extern "C" void kernel_launch(void* const* d_in, const int* in_sizes, int n_in,
                              void* d_out, int out_size, void* d_ws, size_t ws_size,
                              hipStream_t stream) {
    const float* x      = (const float*)d_in[0];
    const float* W1     = (const float*)d_in[1];
    const float* conv_w = (const float*)d_in[2];
    const float* conv_b = (const float*)d_in[3];
    const float* Avec   = (const float*)d_in[4];
    const float* Wb     = (const float*)d_in[5];
    const float* bb     = (const float*)d_in[6];
    const float* Wc     = (const float*)d_in[7];
    const float* bc     = (const float*)d_in[8];
    const float* Wd     = (const float*)d_in[9];
    const float* bd     = (const float*)d_in[10];
    const float* Wdelta = (const float*)d_in[11];
    const float* bdelta = (const float*)d_in[12];
    const float* W2     = (const float*)d_in[13];
    const float* Wlast  = (const float*)d_in[14];
    float* out = (float*)d_out;
    (void)in_sizes; (void)n_in; (void)out_size;

    struct Ptrs {
        u16 *w1, *wdel, *wb, *wd, *wc, *w2, *wl;
        float *cA, *cB, *cH;
        u16 *xb, *x1b, *xab, *delta, *pBv, *ossb, *hstb, *zb;
        size_t total;
    };
    auto layout = [&](int passes) -> Ptrs {
        Ptrs P{};
        const size_t Mp = MROWS / passes;
        const int nb = BATCH / passes;
        size_t off = 0;
        auto al = [&](size_t bytes) -> char* {
            char* p = (char*)d_ws + off; off += (bytes + 255) & ~(size_t)255; return p;
        };
        P.w1   = (u16*)al((size_t)DMODEL*DMODEL*2);
        P.wdel = (u16*)al((size_t)DH*DMODEL*2);
        P.wb   = (u16*)al((size_t)DH*DMODEL*2);
        P.wd   = (u16*)al((size_t)DMODEL*DMODEL*2);
        P.wc   = (u16*)al((size_t)DMODEL*DH*2);
        P.w2   = (u16*)al((size_t)DMODEL*DMODEL*2);
        P.wl   = (u16*)al((size_t)DMODEL*DMODEL*2);
        P.cA  = (float*)al((size_t)nb*NCHUNK*DH*4);
        P.cB  = (float*)al((size_t)nb*NCHUNK*DH*4);
        P.cH  = (float*)al((size_t)nb*NCHUNK*DH*4);
        char* RA = al(Mp*DMODEL*2);                   // xb -> ossb
        char* RB = al(Mp*DMODEL*2);                   // x1b -> zb
        char* RC = al(Mp*DMODEL*2);                   // xab
        char* RD = al(Mp*DH*2);                       // delta
        char* RE = al(Mp*DH*2);                       // pBv
        char* RF = al(Mp*DH*2);                       // hstb
        P.xb    = (u16*)RA; P.ossb = (u16*)RA;
        P.x1b   = (u16*)RB; P.zb   = (u16*)RB;
        P.xab   = (u16*)RC;
        P.delta = (u16*)RD;
        P.pBv   = (u16*)RE;
        P.hstb  = (u16*)RF;
        P.total = off;
        return P;
    };

    int passes = (ws_size >= layout(1).total) ? 1 : 2;
    Ptrs P = layout(passes);
    if (ws_size < P.total) return;
    const int Mp = MROWS / passes;
    const int nb = BATCH / passes;

    const dim3 blk(256);

    // one fused launch: convert all 7 weights into dedicated slots
    {
        CvtArgs a{};
        const float* srcs[7] = { W1, Wdelta, Wb, Wd, Wc, W2, Wlast };
        u16* dsts[7] = { P.w1, P.wdel, P.wb, P.wd, P.wc, P.w2, P.wl };
        const unsigned n4s[7] = {
            DMODEL*DMODEL/4, DH*DMODEL/4, DH*DMODEL/4, DMODEL*DMODEL/4,
            DMODEL*DH/4, DMODEL*DMODEL/4, DMODEL*DMODEL/4 };
        unsigned cum = 0;
        for (int s = 0; s < 7; ++s) { a.src[s] = srcs[s]; a.dst[s] = dsts[s]; a.cum[s] = cum; cum += n4s[s]; }
        a.cum[7] = cum;
        cvt_multi<<<dim3((cum + 255)/256), blk, 0, stream>>>(a);
    }

    const dim3 gD (DMODEL/128, Mp/128);   // 8 x 64 = 512 blocks (1-pass)
    const dim3 gDB(2*DH/128,   Mp/128);   // 32 x 64 = 2048 blocks (merged delta|pBv)

    for (int p = 0; p < passes; ++p) {
        const float* x_p  = x  + (size_t)p*Mp*DMODEL;
        float*      out_p = out + (size_t)p*Mp*DMODEL;

        {   // x -> bf16
            int n4 = (int)((size_t)Mp*DMODEL / 4);
            cvt_bf16<<<dim3((n4 + 255)/256), blk, 0, stream>>>(x_p, P.xb, n4);
        }
        // x1 = x @ W1^T
        gemm_bt<0,false><<<gD, blk, 0, stream>>>(P.xb, P.w1, DMODEL, nullptr, nullptr, 0,
                                                 nullptr, P.x1b, nullptr, nullptr, nullptr, nullptr, Mp, DMODEL);
        // xa = silu(conv3(x1))
        conv_silu8<<<dim3(Mp*DMODEL/8/256), blk, 0, stream>>>(P.x1b, conv_w, conv_b, P.xab);
        // merged: delta = softplus(xa@Wdelta^T + bdelta), pBv = xa@Wb^T + bb
        gemm_bt<4,false><<<gDB, blk, 0, stream>>>(P.xab, P.wdel, DMODEL, nullptr, nullptr, 0,
                                                  nullptr, P.delta, P.pBv, bdelta, bb, nullptr, Mp, 2*DH);
        // chunked scan -> h_st (bf16)
        scan_chunks<<<dim3(DH/2/256, NCHUNK, nb), blk, 0, stream>>>(P.delta, P.pBv, Avec, P.cA, P.cB);
        scan_prefix<<<dim3(nb*DH/256), blk, 0, stream>>>(P.cA, P.cB, P.cH);
        scan_apply <<<dim3(DH/2/256, NCHUNK, nb), blk, 0, stream>>>(P.delta, P.pBv, Avec, P.cH, P.hstb);
        // ossb = bf16(xa @ Wd^T + h_st @ Wc^T + bd + bc)
        gemm_bt<0,true><<<gD, blk, 0, stream>>>(P.xab, P.wd, DMODEL, P.hstb, P.wc, DH,
                                                nullptr, P.ossb, nullptr, bd, bc, nullptr, Mp, DMODEL);
        // z = ossb * silu(ossb @ W2^T)
        gemm_bt<2,false><<<gD, blk, 0, stream>>>(P.ossb, P.w2, DMODEL, nullptr, nullptr, 0,
                                                 nullptr, P.zb, nullptr, nullptr, nullptr, P.ossb, Mp, DMODEL);
        // out = ossb + z @ Wlast^T
        gemm_bt<3,false><<<gD, blk, 0, stream>>>(P.zb, P.wl, DMODEL, nullptr, nullptr, 0,
                                                 out_p, nullptr, nullptr, nullptr, nullptr, P.ossb, Mp, DMODEL);
    }
}